// Round 6
// baseline (136.211 us; speedup 1.0000x reference)
//
#include <hip/hip_runtime.h>
#include <hip/hip_bf16.h>
#include <math.h>

typedef __attribute__((ext_vector_type(8))) short short8;     // 8 x16b = 4 VGPRs (MFMA A/B frag)
typedef __attribute__((ext_vector_type(8))) _Float16 half8;   // f16 MFMA frag
typedef __attribute__((ext_vector_type(4))) float floatx4;    // MFMA C/D frag

#define NB 256
#define NW 16          // waves per block
#define NT (NW * 64)   // 1024 threads
// __launch_bounds__ 2nd arg semantics (measured r0-r4): min BLOCKS/CU clamped by 2048 thr/CU.
// (768,3)->2 blk=24w=6/EU->cap 84 (observed); (1024,4)->2 blk=32w=8/EU->cap 64 (observed, spilled).
// (1024,1) -> 1 blk = 16 waves = 4/EU -> cap 128: fits this kernel's ~84 regs, no spill.

// ---------------- workspace layout (bytes) ----------------
#define WPB_OFF 0u        // 32*288 f16 [oc][k=n*32+ic], rows>=18 zero (p_conv, unscaled)
#define W2B_OFF 18432u    // 32*288 f16, scaled by inv2[oc]
#define W3B_OFF 36864u    // 64*288 f16, scaled by inv3[oc]
#define W1B_OFF 73728u    // 32*32 f16 [oc][k=n*3+ic], k>=27 zero, scaled by inv1[oc]
#define C1S_OFF 75776u    // 32 f32 shift1
#define C2S_OFF 75904u    // 32 f32 shift2
#define C3S_OFF 76032u    // 64 f32 shift3

// ---------------- LDS layout (bytes) ----------------
#define L_IMG1 0            // 785*64 = 50240  (h1: 784 px + zero slot), f16, XOR-swizzled slices
#define L_U    50240        // 785*64 = 50240  (x staging, then h2 interior + zero slot)
#define L_OFFT 100480       // 16 waves * 1536: [0,576) f16 offsets, [576,1344) g/idx records
#define L_WL   125056       // 64 rows * 592 B (wp+w2 rows, later w3 rows)
#define L_TOT  162944

// ---- image slice swizzle ----
// Pixel p occupies 64 B = 4 x 16B slices; stored slice index = s ^ ((p>>1)&3).
// Swizzled base sp = (p<<6) | ((p&6)<<3); consumer of slice s XORs (s<<4).
// Bank start becomes f(p&7) instead of f(p&1): deterministic 8-way -> 2-way (free, m136);
// random bilinear gathers -> ~2.5-way inherent. Zero slot (784) all-zero, swizzle-invariant.

static __device__ __forceinline__ unsigned short f2h(float f) {
    _Float16 h = (_Float16)f;
    unsigned short u;
    __builtin_memcpy(&u, &h, 2);
    return u;
}
static __device__ __forceinline__ float h2f(unsigned short u) {
    _Float16 h;
    __builtin_memcpy(&h, &u, 2);
    return (float)h;
}

// pack two f32 -> packed f16 pair (RNE scalar conversions)
static __device__ __forceinline__ unsigned pkh(float a, float b) {
    _Float16 ha = (_Float16)a, hb = (_Float16)b;
    unsigned short ua, ub;
    __builtin_memcpy(&ua, &ha, 2);
    __builtin_memcpy(&ub, &hb, 2);
    return (unsigned)ua | ((unsigned)ub << 16);
}

static __device__ __forceinline__ half8 h8(uint4 u) {
    half8 r;
    __builtin_memcpy(&r, &u, 16);
    return r;
}

// ---- packed f16 FMA with op_sel broadcast of one half of A ----
static __device__ __forceinline__ unsigned pkmul_l(unsigned a, unsigned b) {
    unsigned d;
    asm("v_pk_mul_f16 %0, %1, %2 op_sel:[0,0] op_sel_hi:[0,1]"
        : "=v"(d) : "v"(a), "v"(b));
    return d;
}
static __device__ __forceinline__ unsigned pkfma_l(unsigned a, unsigned b, unsigned c) {
    unsigned d;
    asm("v_pk_fma_f16 %0, %1, %2, %3 op_sel:[0,0,0] op_sel_hi:[0,1,1]"
        : "=v"(d) : "v"(a), "v"(b), "v"(c));
    return d;
}
static __device__ __forceinline__ unsigned pkfma_h(unsigned a, unsigned b, unsigned c) {
    unsigned d;
    asm("v_pk_fma_f16 %0, %1, %2, %3 op_sel:[1,0,0] op_sel_hi:[1,1,1]"
        : "=v"(d) : "v"(a), "v"(b), "v"(c));
    return d;
}

// ------- weight prep: f16, pre-transposed, BN-scale-folded -------
__global__ void wcvt(const float* __restrict__ wp, const float* __restrict__ w2,
                     const float* __restrict__ w3, const float* __restrict__ w1,
                     const float* __restrict__ g1, const float* __restrict__ b1,
                     const float* __restrict__ m1, const float* __restrict__ v1,
                     const float* __restrict__ g2, const float* __restrict__ b2,
                     const float* __restrict__ m2, const float* __restrict__ v2,
                     const float* __restrict__ g3, const float* __restrict__ b3,
                     const float* __restrict__ m3, const float* __restrict__ v3,
                     unsigned short* __restrict__ wpb, unsigned short* __restrict__ w2b,
                     unsigned short* __restrict__ w3b, unsigned short* __restrict__ w1b,
                     float* __restrict__ c1s, float* __restrict__ c2s,
                     float* __restrict__ c3s)
{
    int t = blockIdx.x * 256 + threadIdx.x;
    if (t < 9216) {
        int oc = t / 288, k = t % 288;
        int n = k >> 5, ic = k & 31;
        wpb[t] = (oc < 18) ? f2h(wp[oc * 288 + ic * 9 + n]) : (unsigned short)0;
    } else if (t < 18432) {
        int i = t - 9216;
        int oc = i / 288, k = i % 288;
        int n = k >> 5, ic = k & 31;
        float inv = g2[oc] * rsqrtf(v2[oc] + 1e-5f);
        w2b[i] = f2h(w2[oc * 288 + ic * 9 + n] * inv);
    } else if (t < 36864) {
        int i = t - 18432;
        int oc = i / 288, k = i % 288;
        int n = k >> 5, ic = k & 31;
        float inv = g3[oc] * rsqrtf(v3[oc] + 1e-5f);
        w3b[i] = f2h(w3[oc * 288 + ic * 9 + n] * inv);
    } else if (t < 37888) {
        int i = t - 36864;        // i = oc*32 + k, k = n*3+ic
        int oc = i >> 5, k = i & 31;
        int n = k / 3, ic = k - n * 3;
        float inv = g1[oc] * rsqrtf(v1[oc] + 1e-5f);
        w1b[i] = (k < 27) ? f2h(w1[oc * 27 + ic * 9 + n] * inv) : (unsigned short)0;
    } else if (t < 37920) {
        int c = t - 37888;        // 0..31
        float inv = g1[c] * rsqrtf(v1[c] + 1e-5f);
        c1s[c] = b1[c] - m1[c] * inv;
    } else if (t < 37952) {
        int c = t - 37920;
        float inv = g2[c] * rsqrtf(v2[c] + 1e-5f);
        c2s[c] = b2[c] - m2[c] * inv;
    } else if (t < 38016) {
        int c = t - 37952;        // 0..63
        float inv = g3[c] * rsqrtf(v3[c] + 1e-5f);
        c3s[c] = b3[c] - m3[c] * inv;
    }
}

// ======= mega-kernel (16 waves): conv1 -> img1 -> p_conv+bilinear+conv2 -> uimg -> conv3+pool -> cls =======
__global__ __launch_bounds__(NT, 1) void meganet(
    const float* __restrict__ x,
    const unsigned short* __restrict__ wpb, const unsigned short* __restrict__ w2b,
    const unsigned short* __restrict__ w3b, const unsigned short* __restrict__ w1b,
    const float* __restrict__ c1s, const float* __restrict__ c2s,
    const float* __restrict__ c3s, const float* __restrict__ bp,
    const float* __restrict__ wc, const float* __restrict__ bc,
    float* __restrict__ outp)
{
    __shared__ __align__(16) unsigned char ALL[L_TOT];
    int t = threadIdx.x, b = blockIdx.x;
    int w = t >> 6, l = t & 63, col = l & 15, q = l >> 4;
    int qs = q << 4;                                           // slice XOR for this lane
    int chxA = ((col >> 3) << 4) | ((col & 7) * 2);            // channel col     (c<16)
    int chxB = ((((16 + col) >> 3) & 3) << 4) | ((col & 7) * 2); // channel 16+col

    unsigned char* img1 = ALL + L_IMG1;
    unsigned char* uimg = ALL + L_U;          // x staging then h2

    // ---- phase 0: stage x + weights into LDS (all coalesced) ----
    {
        const float4* xg = (const float4*)(x + (size_t)b * 2352);
        float4* xl = (float4*)uimg;
        for (int i = t; i < 588; i += NT) xl[i] = xg[i];
    }
    {
        const uint4* s1 = (const uint4*)wpb;
        const uint4* s2 = (const uint4*)w2b;
        for (int i = t; i < 2304; i += NT) {      // wp rows 0..31, w2 rows 32..63
            int row = i / 36, g = i - row * 36;
            uint4 v = (row < 32) ? s1[row * 36 + g] : s2[(row - 32) * 36 + g];
            *(uint4*)(ALL + L_WL + row * 592 + g * 16) = v;
        }
        if (t < 128) *(uint4*)(ALL + L_OFFT + t * 16) = ((const uint4*)w1b)[t];
    }
    if (t == 700) ((float*)uimg)[2352] = 0.f;                       // conv1 zero slot
    if (t < 4)  *(uint4*)(img1 + 784 * 64 + t * 16) = make_uint4(0u, 0u, 0u, 0u);
    if (t >= 4 && t < 8) *(uint4*)(uimg + 784 * 64 + (t - 4) * 16) = make_uint4(0u, 0u, 0u, 0u);

    float s0 = c1s[col], s1v = c1s[16 + col];
    float bias0 = bp[col];
    float bias1 = (col < 2) ? bp[16 + col] : 0.f;
    float sh0 = c2s[col], sh1 = c2s[16 + col];

    __syncthreads();

    // ---- phase 1: conv1 (3->32, pad1, relu, bn-folded) -> img1 (f16, swizzled) ----
    {
        half8 bf0 = h8(*(const uint4*)(ALL + L_OFFT + col * 64 + q * 16));
        half8 bf1 = h8(*(const uint4*)(ALL + L_OFFT + (16 + col) * 64 + q * 16));
        const float* xs = (const float*)uimg;
        for (int mt = w; mt < 49; mt += NW) {
            int p = mt * 16 + col;
            int y = p / 28, xx = p % 28;
            unsigned au[4];
#pragma unroll
            for (int jp = 0; jp < 4; jp++) {
                float vv[2];
#pragma unroll
                for (int h = 0; h < 2; h++) {
                    int k = q * 8 + jp * 2 + h;
                    int n = k / 3, ic = k - n * 3;
                    int yy = y + n / 3 - 1, xc = xx + n % 3 - 1;
                    bool ok = (k < 27) && ((unsigned)yy < 28u) && ((unsigned)xc < 28u);
                    int idx = ok ? (ic * 784 + yy * 28 + xc) : 2352;
                    vv[h] = xs[idx];
                }
                au[jp] = pkh(vv[0], vv[1]);
            }
            uint4 a4 = make_uint4(au[0], au[1], au[2], au[3]);
            half8 a = h8(a4);
            floatx4 d0 = {0.f, 0.f, 0.f, 0.f}, d1 = {0.f, 0.f, 0.f, 0.f};
            d0 = __builtin_amdgcn_mfma_f32_16x16x32_f16(a, bf0, d0, 0, 0, 0);
            d1 = __builtin_amdgcn_mfma_f32_16x16x32_f16(a, bf1, d1, 0, 0, 0);
#pragma unroll
            for (int r = 0; r < 4; r++) {
                int pout = mt * 16 + q * 4 + r;
                int sp = (pout << 6) | ((pout & 6) << 3);
                *(unsigned short*)(img1 + (sp ^ chxA)) = f2h(fmaxf(d0[r], 0.f) + s0);
                *(unsigned short*)(img1 + (sp ^ chxB)) = f2h(fmaxf(d1[r], 0.f) + s1v);
            }
        }
    }
    __syncthreads();

    // ---- phase 2: p_conv MFMA -> offsets(f16) -> per-combo precompute -> record broadcast (LDS)
    //      -> bilinear (packed f16) -> conv2 MFMA -> uimg (swizzled) ----
    {
        const unsigned char* ib = img1;
        unsigned char* wsc = ALL + L_OFFT + w * 1536;
        unsigned short* otw = (unsigned short*)wsc;   // [16 px][18 ch] f16 raw offsets (576 B)
        unsigned char* gscr = wsc + 576;              // 48 records x 16 B {gA,gB,soffA,soffB}

        // hoist conv2 B-frags into registers (loop-invariant; 72 VGPRs)
        half8 b2fr[18];
#pragma unroll
        for (int n = 0; n < 9; n++) {
            b2fr[n]     = h8(*(const uint4*)(ALL + L_WL + (32 + col) * 592 + n * 64 + q * 16));
            b2fr[9 + n] = h8(*(const uint4*)(ALL + L_WL + (48 + col) * 592 + n * 64 + q * 16));
        }

        for (int mt = w; mt < 49; mt += NW) {
            int p = mt * 16 + col;
            int y = p / 28, xx = p % 28;

            // p_conv for this 16-pixel tile (B from LDS pool rows 0..31)
            floatx4 a0 = {0.f, 0.f, 0.f, 0.f}, a1 = {0.f, 0.f, 0.f, 0.f};
#pragma unroll
            for (int n = 0; n < 9; n++) {
                int yy = y + n / 3 - 1, xc = xx + n % 3 - 1;
                bool ok = ((unsigned)yy < 28u) && ((unsigned)xc < 28u);
                int tp = ok ? (yy * 28 + xc) : 784;      // 784 = zero slot
                int sp = (tp << 6) | ((tp & 6) << 3);
                half8 a  = h8(*(const uint4*)(ib + (sp ^ qs)));
                half8 p0 = h8(*(const uint4*)(ALL + L_WL + col * 592 + n * 64 + q * 16));
                half8 p1 = h8(*(const uint4*)(ALL + L_WL + (16 + col) * 592 + n * 64 + q * 16));
                a0 = __builtin_amdgcn_mfma_f32_16x16x32_f16(a, p0, a0, 0, 0, 0);
                a1 = __builtin_amdgcn_mfma_f32_16x16x32_f16(a, p1, a1, 0, 0, 0);
            }
#pragma unroll
            for (int r = 0; r < 4; r++)
                otw[(q * 4 + r) * 18 + col] = f2h(a0[r] + bias0);
            if (col < 2) {
#pragma unroll
                for (int r = 0; r < 4; r++)
                    otw[(q * 4 + r) * 18 + 16 + col] = f2h(a1[r] + bias1);
            }
            __asm__ volatile("s_waitcnt lgkmcnt(0)" ::: "memory");

            floatx4 d0 = {0.f, 0.f, 0.f, 0.f}, d1 = {0.f, 0.f, 0.f, 0.f};
#pragma unroll
            for (int tg = 0; tg < 3; tg++) {
                // precompute: 48 combos (16 px x 3 taps), one per lane l<48
                if (l < 48) {
                    int px = l & 15, n = tg * 3 + (l >> 4);
                    int pg = mt * 16 + px;
                    int yg = pg / 28, xg = pg % 28;
                    float offy = h2f(otw[px * 18 + n]);
                    float offx = h2f(otw[px * 18 + 9 + n]);
                    float py = (float)(yg + n / 3) + offy;       // padded coords
                    float pxf = (float)(xg + n % 3) + offx;
                    float fy = floorf(py), fx = floorf(pxf);
                    float qy0 = fminf(fmaxf(fy, 0.f), 29.f);
                    float qy1 = fminf(fmaxf(fy + 1.f, 0.f), 29.f);
                    float qx0 = fminf(fmaxf(fx, 0.f), 29.f);
                    float qx1 = fminf(fmaxf(fx + 1.f, 0.f), 29.f);
                    float pyc = fminf(fmaxf(py, 0.f), 29.f);
                    float pxc = fminf(fmaxf(pxf, 0.f), 29.f);
                    float glt = (1.f + (qy0 - pyc)) * (1.f + (qx0 - pxc));
                    float grb = (1.f - (qy1 - pyc)) * (1.f - (qx1 - pxc));
                    float glb = (1.f + (qy0 - pyc)) * (1.f - (qx1 - pxc));
                    float grt = (1.f - (qy1 - pyc)) * (1.f + (qx0 - pxc));
                    int iy0 = (int)qy0, iy1 = (int)qy1, ix0 = (int)qx0, ix1 = (int)qx1;
                    int ly0 = iy0 - 1, ly1 = iy1 - 1, lx0 = ix0 - 1, lx1 = ix1 - 1;
                    bool v00 = ((unsigned)ly0 < 28u) && ((unsigned)lx0 < 28u);
                    bool v11 = ((unsigned)ly1 < 28u) && ((unsigned)lx1 < 28u);
                    bool v01 = ((unsigned)ly0 < 28u) && ((unsigned)lx1 < 28u);
                    bool v10 = ((unsigned)ly1 < 28u) && ((unsigned)lx0 < 28u);
                    unsigned p00 = v00 ? (unsigned)(ly0 * 28 + lx0) : 784u;
                    unsigned p11 = v11 ? (unsigned)(ly1 * 28 + lx1) : 784u;
                    unsigned p01 = v01 ? (unsigned)(ly0 * 28 + lx1) : 784u;
                    unsigned p10 = v10 ? (unsigned)(ly1 * 28 + lx0) : 784u;
                    // swizzled base offsets: (p<<6) | ((p&6)<<3) -- consumer XORs (q<<4)
                    unsigned s00 = (p00 << 6) | ((p00 & 6u) << 3);
                    unsigned s11 = (p11 << 6) | ((p11 & 6u) << 3);
                    unsigned s01 = (p01 << 6) | ((p01 & 6u) << 3);
                    unsigned s10 = (p10 << 6) | ((p10 & 6u) << 3);
                    uint4 rec = make_uint4(pkh(glt, grb), pkh(glb, grt),
                                           s00 | (s11 << 16), s01 | (s10 << 16));
                    *(uint4*)(gscr + l * 16) = rec;
                }
                __asm__ volatile("s_waitcnt lgkmcnt(0)" ::: "memory");

                // consume: 3 taps, record broadcast across quads; bilinear in packed f16
#pragma unroll
                for (int k3 = 0; k3 < 3; k3++) {
                    int n = tg * 3 + k3;
                    uint4 rec = *(const uint4*)(gscr + (k3 * 16 + col) * 16);
                    unsigned o00 = (rec.z & 0xffffu) ^ qs, o11 = (rec.z >> 16) ^ qs;
                    unsigned o01 = (rec.w & 0xffffu) ^ qs, o10 = (rec.w >> 16) ^ qs;
                    uint4 u00 = *(const uint4*)(ib + o00);
                    uint4 u11 = *(const uint4*)(ib + o11);
                    uint4 u01 = *(const uint4*)(ib + o01);
                    uint4 u10 = *(const uint4*)(ib + o10);
                    // f = glt*u00 + grb*u11 + glb*u01 + grt*u10, all packed f16
                    unsigned f0 = pkfma_h(rec.y, u10.x,
                                  pkfma_l(rec.y, u01.x,
                                  pkfma_h(rec.x, u11.x,
                                  pkmul_l(rec.x, u00.x))));
                    unsigned f1 = pkfma_h(rec.y, u10.y,
                                  pkfma_l(rec.y, u01.y,
                                  pkfma_h(rec.x, u11.y,
                                  pkmul_l(rec.x, u00.y))));
                    unsigned f2 = pkfma_h(rec.y, u10.z,
                                  pkfma_l(rec.y, u01.z,
                                  pkfma_h(rec.x, u11.z,
                                  pkmul_l(rec.x, u00.z))));
                    unsigned f3 = pkfma_h(rec.y, u10.w,
                                  pkfma_l(rec.y, u01.w,
                                  pkfma_h(rec.x, u11.w,
                                  pkmul_l(rec.x, u00.w))));
                    uint4 af4 = make_uint4(f0, f1, f2, f3);
                    half8 af = h8(af4);
                    d0 = __builtin_amdgcn_mfma_f32_16x16x32_f16(af, b2fr[n], d0, 0, 0, 0);
                    d1 = __builtin_amdgcn_mfma_f32_16x16x32_f16(af, b2fr[9 + n], d1, 0, 0, 0);
                }
            }
            // relu + shift2 + store to LDS uimg (swizzled, 64B/px, f16)
#pragma unroll
            for (int r = 0; r < 4; r++) {
                int pout = mt * 16 + q * 4 + r;
                int sp = (pout << 6) | ((pout & 6) << 3);
                *(unsigned short*)(uimg + (sp ^ chxA)) = f2h(fmaxf(d0[r], 0.f) + sh0);
                *(unsigned short*)(uimg + (sp ^ chxB)) = f2h(fmaxf(d1[r], 0.f) + sh1);
            }
        }
    }
    __syncthreads();

    // ---- phase 3: stage w3 (f16, pre-scaled) -> pool rows 0..63 (coalesced) ----
    {
        const uint4* src = (const uint4*)w3b;
        for (int i = t; i < 2304; i += NT) {
            int row = i / 36, g = i - row * 36;
            *(uint4*)(ALL + L_WL + row * 592 + g * 16) = src[row * 36 + g];
        }
    }
    __syncthreads();

    // ---- phase 4: conv3 MFMA + relu + global-sum partials (weights hoisted to VGPRs) ----
    {
        float* part = (float*)(ALL + L_OFFT);   // [NW][32]
        int ocp = w & 1;
        const unsigned char* ib = uimg;

        half8 wfr[18];
#pragma unroll
        for (int n = 0; n < 9; n++) {
            wfr[n]     = h8(*(const uint4*)(ALL + L_WL + (ocp * 32 + col) * 592 + n * 64 + q * 16));
            wfr[9 + n] = h8(*(const uint4*)(ALL + L_WL + (ocp * 32 + 16 + col) * 592 + n * 64 + q * 16));
        }

        float psA = 0.f, psB = 0.f;
        for (int mt = (w >> 1); mt < 49; mt += (NW / 2)) {
            int p = mt * 16 + col;
            int y = p / 28, xx = p % 28;
            floatx4 cA = {0.f, 0.f, 0.f, 0.f}, cB = {0.f, 0.f, 0.f, 0.f};
#pragma unroll
            for (int n = 0; n < 9; n++) {
                int yy = y + n / 3 - 1, xc = xx + n % 3 - 1;
                bool ok = ((unsigned)yy < 28u) && ((unsigned)xc < 28u);
                int tp = ok ? (yy * 28 + xc) : 784;
                int sp = (tp << 6) | ((tp & 6) << 3);
                half8 a = h8(*(const uint4*)(ib + (sp ^ qs)));
                cA = __builtin_amdgcn_mfma_f32_16x16x32_f16(a, wfr[n], cA, 0, 0, 0);
                cB = __builtin_amdgcn_mfma_f32_16x16x32_f16(a, wfr[9 + n], cB, 0, 0, 0);
            }
            psA += fmaxf(cA[0], 0.f) + fmaxf(cA[1], 0.f) + fmaxf(cA[2], 0.f) + fmaxf(cA[3], 0.f);
            psB += fmaxf(cB[0], 0.f) + fmaxf(cB[1], 0.f) + fmaxf(cB[2], 0.f) + fmaxf(cB[3], 0.f);
        }
        psA += __shfl_xor(psA, 16, 64); psA += __shfl_xor(psA, 32, 64);
        psB += __shfl_xor(psB, 16, 64); psB += __shfl_xor(psB, 32, 64);
        if (l < 16) { part[w * 32 + l] = psA; part[w * 32 + 16 + l] = psB; }
    }
    __syncthreads();

    // ---- phase 5: classifier (one wave): shift3, mean, linear 64->10, log_softmax ----
    if (t < 64) {
        const float* part = (const float*)(ALL + L_OFFT);
        int hi = t >> 5, c = t & 31;
        float s = 0.f;
#pragma unroll
        for (int j = 0; j < NW / 2; j++) s += part[(2 * j + hi) * 32 + c];   // oc = t
        float feat = s * (1.f / 784.f) + c3s[t];
        float lg[10];
        float mx = -1e30f;
#pragma unroll
        for (int j = 0; j < 10; j++) {
            float v = feat * wc[j * 64 + t];
            v += __shfl_xor(v, 1, 64);  v += __shfl_xor(v, 2, 64);
            v += __shfl_xor(v, 4, 64);  v += __shfl_xor(v, 8, 64);
            v += __shfl_xor(v, 16, 64); v += __shfl_xor(v, 32, 64);
            lg[j] = v + bc[j];
            mx = fmaxf(mx, lg[j]);
        }
        float se = 0.f;
#pragma unroll
        for (int j = 0; j < 10; j++) se += expf(lg[j] - mx);
        float lse = logf(se);
#pragma unroll
        for (int j = 0; j < 10; j++)
            if (t == j) outp[(size_t)b * 10 + j] = lg[j] - mx - lse;
    }
}

extern "C" void kernel_launch(void* const* d_in, const int* in_sizes, int n_in,
                              void* d_out, int out_size, void* d_ws, size_t ws_size,
                              hipStream_t stream)
{
    (void)in_sizes; (void)n_in; (void)out_size; (void)ws_size;
    const float* x  = (const float*)d_in[0];
    const float* w1 = (const float*)d_in[1];
    const float* g1 = (const float*)d_in[2];
    const float* b1 = (const float*)d_in[3];
    const float* m1 = (const float*)d_in[4];
    const float* v1 = (const float*)d_in[5];
    const float* wp = (const float*)d_in[6];
    const float* bp = (const float*)d_in[7];
    const float* w2 = (const float*)d_in[8];
    const float* g2 = (const float*)d_in[9];
    const float* b2 = (const float*)d_in[10];
    const float* m2 = (const float*)d_in[11];
    const float* v2 = (const float*)d_in[12];
    const float* w3 = (const float*)d_in[13];
    const float* g3 = (const float*)d_in[14];
    const float* b3 = (const float*)d_in[15];
    const float* m3 = (const float*)d_in[16];
    const float* v3 = (const float*)d_in[17];
    const float* wc = (const float*)d_in[18];
    const float* bc = (const float*)d_in[19];
    float* outp = (float*)d_out;

    unsigned char* ws = (unsigned char*)d_ws;
    unsigned short* wpb = (unsigned short*)(ws + WPB_OFF);
    unsigned short* w2b = (unsigned short*)(ws + W2B_OFF);
    unsigned short* w3b = (unsigned short*)(ws + W3B_OFF);
    unsigned short* w1b = (unsigned short*)(ws + W1B_OFF);
    float* c1s = (float*)(ws + C1S_OFF);
    float* c2s = (float*)(ws + C2S_OFF);
    float* c3s = (float*)(ws + C3S_OFF);

    wcvt<<<149, 256, 0, stream>>>(wp, w2, w3, w1, g1, b1, m1, v1,
                                  g2, b2, m2, v2, g3, b3, m3, v3,
                                  wpb, w2b, w3b, w1b, c1s, c2s, c3s);
    meganet<<<NB, NT, 0, stream>>>(x, wpb, w2b, w3b, w1b, c1s, c2s, c3s,
                                   bp, wc, bc, outp);
}

// Round 7
// 128.148 us; speedup vs baseline: 1.0629x; 1.0629x over previous
//
#include <hip/hip_runtime.h>
#include <hip/hip_bf16.h>
#include <math.h>

typedef __attribute__((ext_vector_type(8))) short short8;     // 8 x16b = 4 VGPRs (MFMA A/B frag)
typedef __attribute__((ext_vector_type(8))) _Float16 half8;   // f16 MFMA frag
typedef __attribute__((ext_vector_type(4))) float floatx4;    // MFMA C/D frag

#define NB 256
#define NW 12          // waves per block. 1024-thr blocks pin VGPR cap to 64 on this toolchain
#define NT (NW * 64)   // (r3/r6: (1024,4) and (1024,1) both -> 64 VGPR + MB-scale spills). 768 it is.

// ---------------- workspace layout (bytes) ----------------
#define WPB_OFF 0u        // 32*288 f16 [oc][k=n*32+ic], rows>=18 zero (p_conv, unscaled)
#define W2B_OFF 18432u    // 32*288 f16, scaled by inv2[oc]
#define W3B_OFF 36864u    // 64*288 f16, scaled by inv3[oc]
#define W1B_OFF 73728u    // 32*32 f16 [oc][k=n*3+ic], k>=27 zero, scaled by inv1[oc]
#define C1S_OFF 75776u    // 32 f32 shift1
#define C2S_OFF 75904u    // 32 f32 shift2
#define C3S_OFF 76032u    // 64 f32 shift3

// ---------------- LDS layout (bytes) ----------------
#define L_IMG1 0            // 785*64 = 50240  (h1: 784 px + zero slot), f16, XOR-swizzled slices
#define L_U    50240        // 785*64 = 50240  (x staging, then h2 interior + zero slot)
#define L_OFFT 100480       // 12 waves * 1536: [0,576) f16 offsets, [576,1344) g/idx records
#define L_WL   125056       // 64 rows * 592 B (wp+w2 rows, later w3 rows)
#define L_TOT  162944

// ---- image slice swizzle ----
// Pixel p occupies 64 B = 4 x 16B slices; stored slice index = s ^ ((p>>1)&3).
// Swizzled base sp = (p<<6) | ((p&6)<<3); consumer of slice s XORs (s<<4).
// Bank start becomes f(p&7) instead of f(p&1): deterministic 8-way -> 2-way (free, m136);
// random bilinear gathers -> ~2.5-way inherent. Zero slot (784) all-zero, swizzle-invariant.

// ---- intra-wave LDS ordering ----
// otw / gscr are PER-WAVE private scratch. DS ops from one wave are serviced in
// program order (LGKM decrements for DS are in-order), so the compiler's counted
// lgkmcnt before using a read result also covers the preceding ds_write. Hard
// `s_waitcnt lgkmcnt(0)` walls are NOT needed -- only a compile-time fence to
// keep the write textually before the read. (r7 experiment; falsifier = absmax.)
#define LDS_FENCE() __asm__ volatile("" ::: "memory")

static __device__ __forceinline__ unsigned short f2h(float f) {
    _Float16 h = (_Float16)f;
    unsigned short u;
    __builtin_memcpy(&u, &h, 2);
    return u;
}
static __device__ __forceinline__ float h2f(unsigned short u) {
    _Float16 h;
    __builtin_memcpy(&h, &u, 2);
    return (float)h;
}

// pack two f32 -> packed f16 pair (RNE scalar conversions)
static __device__ __forceinline__ unsigned pkh(float a, float b) {
    _Float16 ha = (_Float16)a, hb = (_Float16)b;
    unsigned short ua, ub;
    __builtin_memcpy(&ua, &ha, 2);
    __builtin_memcpy(&ub, &hb, 2);
    return (unsigned)ua | ((unsigned)ub << 16);
}

static __device__ __forceinline__ half8 h8(uint4 u) {
    half8 r;
    __builtin_memcpy(&r, &u, 16);
    return r;
}

// ---- packed f16 FMA with op_sel broadcast of one half of A ----
static __device__ __forceinline__ unsigned pkmul_l(unsigned a, unsigned b) {
    unsigned d;
    asm("v_pk_mul_f16 %0, %1, %2 op_sel:[0,0] op_sel_hi:[0,1]"
        : "=v"(d) : "v"(a), "v"(b));
    return d;
}
static __device__ __forceinline__ unsigned pkfma_l(unsigned a, unsigned b, unsigned c) {
    unsigned d;
    asm("v_pk_fma_f16 %0, %1, %2, %3 op_sel:[0,0,0] op_sel_hi:[0,1,1]"
        : "=v"(d) : "v"(a), "v"(b), "v"(c));
    return d;
}
static __device__ __forceinline__ unsigned pkfma_h(unsigned a, unsigned b, unsigned c) {
    unsigned d;
    asm("v_pk_fma_f16 %0, %1, %2, %3 op_sel:[1,0,0] op_sel_hi:[1,1,1]"
        : "=v"(d) : "v"(a), "v"(b), "v"(c));
    return d;
}

// ------- weight prep: f16, pre-transposed, BN-scale-folded -------
__global__ void wcvt(const float* __restrict__ wp, const float* __restrict__ w2,
                     const float* __restrict__ w3, const float* __restrict__ w1,
                     const float* __restrict__ g1, const float* __restrict__ b1,
                     const float* __restrict__ m1, const float* __restrict__ v1,
                     const float* __restrict__ g2, const float* __restrict__ b2,
                     const float* __restrict__ m2, const float* __restrict__ v2,
                     const float* __restrict__ g3, const float* __restrict__ b3,
                     const float* __restrict__ m3, const float* __restrict__ v3,
                     unsigned short* __restrict__ wpb, unsigned short* __restrict__ w2b,
                     unsigned short* __restrict__ w3b, unsigned short* __restrict__ w1b,
                     float* __restrict__ c1s, float* __restrict__ c2s,
                     float* __restrict__ c3s)
{
    int t = blockIdx.x * 256 + threadIdx.x;
    if (t < 9216) {
        int oc = t / 288, k = t % 288;
        int n = k >> 5, ic = k & 31;
        wpb[t] = (oc < 18) ? f2h(wp[oc * 288 + ic * 9 + n]) : (unsigned short)0;
    } else if (t < 18432) {
        int i = t - 9216;
        int oc = i / 288, k = i % 288;
        int n = k >> 5, ic = k & 31;
        float inv = g2[oc] * rsqrtf(v2[oc] + 1e-5f);
        w2b[i] = f2h(w2[oc * 288 + ic * 9 + n] * inv);
    } else if (t < 36864) {
        int i = t - 18432;
        int oc = i / 288, k = i % 288;
        int n = k >> 5, ic = k & 31;
        float inv = g3[oc] * rsqrtf(v3[oc] + 1e-5f);
        w3b[i] = f2h(w3[oc * 288 + ic * 9 + n] * inv);
    } else if (t < 37888) {
        int i = t - 36864;        // i = oc*32 + k, k = n*3+ic
        int oc = i >> 5, k = i & 31;
        int n = k / 3, ic = k - n * 3;
        float inv = g1[oc] * rsqrtf(v1[oc] + 1e-5f);
        w1b[i] = (k < 27) ? f2h(w1[oc * 27 + ic * 9 + n] * inv) : (unsigned short)0;
    } else if (t < 37920) {
        int c = t - 37888;        // 0..31
        float inv = g1[c] * rsqrtf(v1[c] + 1e-5f);
        c1s[c] = b1[c] - m1[c] * inv;
    } else if (t < 37952) {
        int c = t - 37920;
        float inv = g2[c] * rsqrtf(v2[c] + 1e-5f);
        c2s[c] = b2[c] - m2[c] * inv;
    } else if (t < 38016) {
        int c = t - 37952;        // 0..63
        float inv = g3[c] * rsqrtf(v3[c] + 1e-5f);
        c3s[c] = b3[c] - m3[c] * inv;
    }
}

// ======= mega-kernel (12 waves): conv1 -> img1 -> p_conv+bilinear+conv2 -> uimg -> conv3+pool -> cls =======
__global__ __launch_bounds__(NT, 3) void meganet(
    const float* __restrict__ x,
    const unsigned short* __restrict__ wpb, const unsigned short* __restrict__ w2b,
    const unsigned short* __restrict__ w3b, const unsigned short* __restrict__ w1b,
    const float* __restrict__ c1s, const float* __restrict__ c2s,
    const float* __restrict__ c3s, const float* __restrict__ bp,
    const float* __restrict__ wc, const float* __restrict__ bc,
    float* __restrict__ outp)
{
    __shared__ __align__(16) unsigned char ALL[L_TOT];
    int t = threadIdx.x, b = blockIdx.x;
    int w = t >> 6, l = t & 63, col = l & 15, q = l >> 4;
    int qs = q << 4;                                           // slice XOR for this lane
    int chxA = ((col >> 3) << 4) | ((col & 7) * 2);            // channel col     (c<16)
    int chxB = ((((16 + col) >> 3) & 3) << 4) | ((col & 7) * 2); // channel 16+col

    unsigned char* img1 = ALL + L_IMG1;
    unsigned char* uimg = ALL + L_U;          // x staging then h2

    // ---- phase 0: stage x + weights into LDS (all coalesced) ----
    {
        const float4* xg = (const float4*)(x + (size_t)b * 2352);
        float4* xl = (float4*)uimg;
        for (int i = t; i < 588; i += NT) xl[i] = xg[i];
    }
    {
        const uint4* s1 = (const uint4*)wpb;
        const uint4* s2 = (const uint4*)w2b;
        for (int i = t; i < 2304; i += NT) {      // wp rows 0..31, w2 rows 32..63
            int row = i / 36, g = i - row * 36;
            uint4 v = (row < 32) ? s1[row * 36 + g] : s2[(row - 32) * 36 + g];
            *(uint4*)(ALL + L_WL + row * 592 + g * 16) = v;
        }
        if (t < 128) *(uint4*)(ALL + L_OFFT + t * 16) = ((const uint4*)w1b)[t];
    }
    if (t == 700) ((float*)uimg)[2352] = 0.f;                       // conv1 zero slot
    if (t < 4)  *(uint4*)(img1 + 784 * 64 + t * 16) = make_uint4(0u, 0u, 0u, 0u);
    if (t >= 4 && t < 8) *(uint4*)(uimg + 784 * 64 + (t - 4) * 16) = make_uint4(0u, 0u, 0u, 0u);

    float s0 = c1s[col], s1v = c1s[16 + col];
    float bias0 = bp[col];
    float bias1 = (col < 2) ? bp[16 + col] : 0.f;
    float sh0 = c2s[col], sh1 = c2s[16 + col];

    __syncthreads();

    // ---- phase 1: conv1 (3->32, pad1, relu, bn-folded) -> img1 (f16, swizzled) ----
    {
        half8 bf0 = h8(*(const uint4*)(ALL + L_OFFT + col * 64 + q * 16));
        half8 bf1 = h8(*(const uint4*)(ALL + L_OFFT + (16 + col) * 64 + q * 16));
        const float* xs = (const float*)uimg;
        for (int mt = w; mt < 49; mt += NW) {
            int p = mt * 16 + col;
            int y = p / 28, xx = p % 28;
            unsigned au[4];
#pragma unroll
            for (int jp = 0; jp < 4; jp++) {
                float vv[2];
#pragma unroll
                for (int h = 0; h < 2; h++) {
                    int k = q * 8 + jp * 2 + h;
                    int n = k / 3, ic = k - n * 3;
                    int yy = y + n / 3 - 1, xc = xx + n % 3 - 1;
                    bool ok = (k < 27) && ((unsigned)yy < 28u) && ((unsigned)xc < 28u);
                    int idx = ok ? (ic * 784 + yy * 28 + xc) : 2352;
                    vv[h] = xs[idx];
                }
                au[jp] = pkh(vv[0], vv[1]);
            }
            uint4 a4 = make_uint4(au[0], au[1], au[2], au[3]);
            half8 a = h8(a4);
            floatx4 d0 = {0.f, 0.f, 0.f, 0.f}, d1 = {0.f, 0.f, 0.f, 0.f};
            d0 = __builtin_amdgcn_mfma_f32_16x16x32_f16(a, bf0, d0, 0, 0, 0);
            d1 = __builtin_amdgcn_mfma_f32_16x16x32_f16(a, bf1, d1, 0, 0, 0);
#pragma unroll
            for (int r = 0; r < 4; r++) {
                int pout = mt * 16 + q * 4 + r;
                int sp = (pout << 6) | ((pout & 6) << 3);
                *(unsigned short*)(img1 + (sp ^ chxA)) = f2h(fmaxf(d0[r], 0.f) + s0);
                *(unsigned short*)(img1 + (sp ^ chxB)) = f2h(fmaxf(d1[r], 0.f) + s1v);
            }
        }
    }
    __syncthreads();

    // ---- phase 2: p_conv MFMA -> offsets(f16) -> per-combo precompute -> record broadcast (LDS)
    //      -> bilinear (packed f16) -> conv2 MFMA -> uimg (swizzled) ----
    {
        const unsigned char* ib = img1;
        unsigned char* wsc = ALL + L_OFFT + w * 1536;
        unsigned short* otw = (unsigned short*)wsc;   // [16 px][18 ch] f16 raw offsets (576 B)
        unsigned char* gscr = wsc + 576;              // 48 records x 16 B {gA,gB,soffA,soffB}

        // hoist conv2 B-frags into registers (loop-invariant; 72 VGPRs)
        half8 b2fr[18];
#pragma unroll
        for (int n = 0; n < 9; n++) {
            b2fr[n]     = h8(*(const uint4*)(ALL + L_WL + (32 + col) * 592 + n * 64 + q * 16));
            b2fr[9 + n] = h8(*(const uint4*)(ALL + L_WL + (48 + col) * 592 + n * 64 + q * 16));
        }

        for (int mt = w; mt < 49; mt += NW) {
            int p = mt * 16 + col;
            int y = p / 28, xx = p % 28;

            // p_conv for this 16-pixel tile (B from LDS pool rows 0..31)
            floatx4 a0 = {0.f, 0.f, 0.f, 0.f}, a1 = {0.f, 0.f, 0.f, 0.f};
#pragma unroll
            for (int n = 0; n < 9; n++) {
                int yy = y + n / 3 - 1, xc = xx + n % 3 - 1;
                bool ok = ((unsigned)yy < 28u) && ((unsigned)xc < 28u);
                int tp = ok ? (yy * 28 + xc) : 784;      // 784 = zero slot
                int sp = (tp << 6) | ((tp & 6) << 3);
                half8 a  = h8(*(const uint4*)(ib + (sp ^ qs)));
                half8 p0 = h8(*(const uint4*)(ALL + L_WL + col * 592 + n * 64 + q * 16));
                half8 p1 = h8(*(const uint4*)(ALL + L_WL + (16 + col) * 592 + n * 64 + q * 16));
                a0 = __builtin_amdgcn_mfma_f32_16x16x32_f16(a, p0, a0, 0, 0, 0);
                a1 = __builtin_amdgcn_mfma_f32_16x16x32_f16(a, p1, a1, 0, 0, 0);
            }
#pragma unroll
            for (int r = 0; r < 4; r++)
                otw[(q * 4 + r) * 18 + col] = f2h(a0[r] + bias0);
            if (col < 2) {
#pragma unroll
                for (int r = 0; r < 4; r++)
                    otw[(q * 4 + r) * 18 + 16 + col] = f2h(a1[r] + bias1);
            }
            LDS_FENCE();   // per-wave buffer: in-order DS pipe makes the write visible to later reads

            floatx4 d0 = {0.f, 0.f, 0.f, 0.f}, d1 = {0.f, 0.f, 0.f, 0.f};
#pragma unroll
            for (int tg = 0; tg < 3; tg++) {
                // precompute: 48 combos (16 px x 3 taps), one per lane l<48
                if (l < 48) {
                    int px = l & 15, n = tg * 3 + (l >> 4);
                    int pg = mt * 16 + px;
                    int yg = pg / 28, xg = pg % 28;
                    float offy = h2f(otw[px * 18 + n]);
                    float offx = h2f(otw[px * 18 + 9 + n]);
                    float py = (float)(yg + n / 3) + offy;       // padded coords
                    float pxf = (float)(xg + n % 3) + offx;
                    float fy = floorf(py), fx = floorf(pxf);
                    float qy0 = fminf(fmaxf(fy, 0.f), 29.f);
                    float qy1 = fminf(fmaxf(fy + 1.f, 0.f), 29.f);
                    float qx0 = fminf(fmaxf(fx, 0.f), 29.f);
                    float qx1 = fminf(fmaxf(fx + 1.f, 0.f), 29.f);
                    float pyc = fminf(fmaxf(py, 0.f), 29.f);
                    float pxc = fminf(fmaxf(pxf, 0.f), 29.f);
                    float glt = (1.f + (qy0 - pyc)) * (1.f + (qx0 - pxc));
                    float grb = (1.f - (qy1 - pyc)) * (1.f - (qx1 - pxc));
                    float glb = (1.f + (qy0 - pyc)) * (1.f - (qx1 - pxc));
                    float grt = (1.f - (qy1 - pyc)) * (1.f + (qx0 - pxc));
                    int iy0 = (int)qy0, iy1 = (int)qy1, ix0 = (int)qx0, ix1 = (int)qx1;
                    int ly0 = iy0 - 1, ly1 = iy1 - 1, lx0 = ix0 - 1, lx1 = ix1 - 1;
                    bool v00 = ((unsigned)ly0 < 28u) && ((unsigned)lx0 < 28u);
                    bool v11 = ((unsigned)ly1 < 28u) && ((unsigned)lx1 < 28u);
                    bool v01 = ((unsigned)ly0 < 28u) && ((unsigned)lx1 < 28u);
                    bool v10 = ((unsigned)ly1 < 28u) && ((unsigned)lx0 < 28u);
                    unsigned p00 = v00 ? (unsigned)(ly0 * 28 + lx0) : 784u;
                    unsigned p11 = v11 ? (unsigned)(ly1 * 28 + lx1) : 784u;
                    unsigned p01 = v01 ? (unsigned)(ly0 * 28 + lx1) : 784u;
                    unsigned p10 = v10 ? (unsigned)(ly1 * 28 + lx0) : 784u;
                    // swizzled base offsets: (p<<6) | ((p&6)<<3) -- consumer XORs (q<<4)
                    unsigned s00 = (p00 << 6) | ((p00 & 6u) << 3);
                    unsigned s11 = (p11 << 6) | ((p11 & 6u) << 3);
                    unsigned s01 = (p01 << 6) | ((p01 & 6u) << 3);
                    unsigned s10 = (p10 << 6) | ((p10 & 6u) << 3);
                    uint4 rec = make_uint4(pkh(glt, grb), pkh(glb, grt),
                                           s00 | (s11 << 16), s01 | (s10 << 16));
                    *(uint4*)(gscr + l * 16) = rec;
                }
                LDS_FENCE();   // same-wave gscr write -> read: in-order DS pipe

                // consume: 3 taps, record broadcast across quads; bilinear in packed f16
#pragma unroll
                for (int k3 = 0; k3 < 3; k3++) {
                    int n = tg * 3 + k3;
                    uint4 rec = *(const uint4*)(gscr + (k3 * 16 + col) * 16);
                    unsigned o00 = (rec.z & 0xffffu) ^ qs, o11 = (rec.z >> 16) ^ qs;
                    unsigned o01 = (rec.w & 0xffffu) ^ qs, o10 = (rec.w >> 16) ^ qs;
                    uint4 u00 = *(const uint4*)(ib + o00);
                    uint4 u11 = *(const uint4*)(ib + o11);
                    uint4 u01 = *(const uint4*)(ib + o01);
                    uint4 u10 = *(const uint4*)(ib + o10);
                    // f = glt*u00 + grb*u11 + glb*u01 + grt*u10, all packed f16
                    unsigned f0 = pkfma_h(rec.y, u10.x,
                                  pkfma_l(rec.y, u01.x,
                                  pkfma_h(rec.x, u11.x,
                                  pkmul_l(rec.x, u00.x))));
                    unsigned f1 = pkfma_h(rec.y, u10.y,
                                  pkfma_l(rec.y, u01.y,
                                  pkfma_h(rec.x, u11.y,
                                  pkmul_l(rec.x, u00.y))));
                    unsigned f2 = pkfma_h(rec.y, u10.z,
                                  pkfma_l(rec.y, u01.z,
                                  pkfma_h(rec.x, u11.z,
                                  pkmul_l(rec.x, u00.z))));
                    unsigned f3 = pkfma_h(rec.y, u10.w,
                                  pkfma_l(rec.y, u01.w,
                                  pkfma_h(rec.x, u11.w,
                                  pkmul_l(rec.x, u00.w))));
                    uint4 af4 = make_uint4(f0, f1, f2, f3);
                    half8 af = h8(af4);
                    d0 = __builtin_amdgcn_mfma_f32_16x16x32_f16(af, b2fr[n], d0, 0, 0, 0);
                    d1 = __builtin_amdgcn_mfma_f32_16x16x32_f16(af, b2fr[9 + n], d1, 0, 0, 0);
                }
            }
            // relu + shift2 + store to LDS uimg (swizzled, 64B/px, f16)
#pragma unroll
            for (int r = 0; r < 4; r++) {
                int pout = mt * 16 + q * 4 + r;
                int sp = (pout << 6) | ((pout & 6) << 3);
                *(unsigned short*)(uimg + (sp ^ chxA)) = f2h(fmaxf(d0[r], 0.f) + sh0);
                *(unsigned short*)(uimg + (sp ^ chxB)) = f2h(fmaxf(d1[r], 0.f) + sh1);
            }
        }
    }
    __syncthreads();

    // ---- phase 3: stage w3 (f16, pre-scaled) -> pool rows 0..63 (coalesced) ----
    {
        const uint4* src = (const uint4*)w3b;
        for (int i = t; i < 2304; i += NT) {
            int row = i / 36, g = i - row * 36;
            *(uint4*)(ALL + L_WL + row * 592 + g * 16) = src[row * 36 + g];
        }
    }
    __syncthreads();

    // ---- phase 4: conv3 MFMA + relu + global-sum partials (weights hoisted to VGPRs) ----
    {
        float* part = (float*)(ALL + L_OFFT);   // [NW][32]
        int ocp = w & 1;
        const unsigned char* ib = uimg;

        half8 wfr[18];
#pragma unroll
        for (int n = 0; n < 9; n++) {
            wfr[n]     = h8(*(const uint4*)(ALL + L_WL + (ocp * 32 + col) * 592 + n * 64 + q * 16));
            wfr[9 + n] = h8(*(const uint4*)(ALL + L_WL + (ocp * 32 + 16 + col) * 592 + n * 64 + q * 16));
        }

        float psA = 0.f, psB = 0.f;
        for (int mt = (w >> 1); mt < 49; mt += (NW / 2)) {
            int p = mt * 16 + col;
            int y = p / 28, xx = p % 28;
            floatx4 cA = {0.f, 0.f, 0.f, 0.f}, cB = {0.f, 0.f, 0.f, 0.f};
#pragma unroll
            for (int n = 0; n < 9; n++) {
                int yy = y + n / 3 - 1, xc = xx + n % 3 - 1;
                bool ok = ((unsigned)yy < 28u) && ((unsigned)xc < 28u);
                int tp = ok ? (yy * 28 + xc) : 784;
                int sp = (tp << 6) | ((tp & 6) << 3);
                half8 a = h8(*(const uint4*)(ib + (sp ^ qs)));
                cA = __builtin_amdgcn_mfma_f32_16x16x32_f16(a, wfr[n], cA, 0, 0, 0);
                cB = __builtin_amdgcn_mfma_f32_16x16x32_f16(a, wfr[9 + n], cB, 0, 0, 0);
            }
            psA += fmaxf(cA[0], 0.f) + fmaxf(cA[1], 0.f) + fmaxf(cA[2], 0.f) + fmaxf(cA[3], 0.f);
            psB += fmaxf(cB[0], 0.f) + fmaxf(cB[1], 0.f) + fmaxf(cB[2], 0.f) + fmaxf(cB[3], 0.f);
        }
        psA += __shfl_xor(psA, 16, 64); psA += __shfl_xor(psA, 32, 64);
        psB += __shfl_xor(psB, 16, 64); psB += __shfl_xor(psB, 32, 64);
        if (l < 16) { part[w * 32 + l] = psA; part[w * 32 + 16 + l] = psB; }
    }
    __syncthreads();

    // ---- phase 5: classifier (one wave): shift3, mean, linear 64->10, log_softmax ----
    if (t < 64) {
        const float* part = (const float*)(ALL + L_OFFT);
        int hi = t >> 5, c = t & 31;
        float s = 0.f;
#pragma unroll
        for (int j = 0; j < NW / 2; j++) s += part[(2 * j + hi) * 32 + c];   // oc = t
        float feat = s * (1.f / 784.f) + c3s[t];
        float lg[10];
        float mx = -1e30f;
#pragma unroll
        for (int j = 0; j < 10; j++) {
            float v = feat * wc[j * 64 + t];
            v += __shfl_xor(v, 1, 64);  v += __shfl_xor(v, 2, 64);
            v += __shfl_xor(v, 4, 64);  v += __shfl_xor(v, 8, 64);
            v += __shfl_xor(v, 16, 64); v += __shfl_xor(v, 32, 64);
            lg[j] = v + bc[j];
            mx = fmaxf(mx, lg[j]);
        }
        float se = 0.f;
#pragma unroll
        for (int j = 0; j < 10; j++) se += expf(lg[j] - mx);
        float lse = logf(se);
#pragma unroll
        for (int j = 0; j < 10; j++)
            if (t == j) outp[(size_t)b * 10 + j] = lg[j] - mx - lse;
    }
}

extern "C" void kernel_launch(void* const* d_in, const int* in_sizes, int n_in,
                              void* d_out, int out_size, void* d_ws, size_t ws_size,
                              hipStream_t stream)
{
    (void)in_sizes; (void)n_in; (void)out_size; (void)ws_size;
    const float* x  = (const float*)d_in[0];
    const float* w1 = (const float*)d_in[1];
    const float* g1 = (const float*)d_in[2];
    const float* b1 = (const float*)d_in[3];
    const float* m1 = (const float*)d_in[4];
    const float* v1 = (const float*)d_in[5];
    const float* wp = (const float*)d_in[6];
    const float* bp = (const float*)d_in[7];
    const float* w2 = (const float*)d_in[8];
    const float* g2 = (const float*)d_in[9];
    const float* b2 = (const float*)d_in[10];
    const float* m2 = (const float*)d_in[11];
    const float* v2 = (const float*)d_in[12];
    const float* w3 = (const float*)d_in[13];
    const float* g3 = (const float*)d_in[14];
    const float* b3 = (const float*)d_in[15];
    const float* m3 = (const float*)d_in[16];
    const float* v3 = (const float*)d_in[17];
    const float* wc = (const float*)d_in[18];
    const float* bc = (const float*)d_in[19];
    float* outp = (float*)d_out;

    unsigned char* ws = (unsigned char*)d_ws;
    unsigned short* wpb = (unsigned short*)(ws + WPB_OFF);
    unsigned short* w2b = (unsigned short*)(ws + W2B_OFF);
    unsigned short* w3b = (unsigned short*)(ws + W3B_OFF);
    unsigned short* w1b = (unsigned short*)(ws + W1B_OFF);
    float* c1s = (float*)(ws + C1S_OFF);
    float* c2s = (float*)(ws + C2S_OFF);
    float* c3s = (float*)(ws + C3S_OFF);

    wcvt<<<149, 256, 0, stream>>>(wp, w2, w3, w1, g1, b1, m1, v1,
                                  g2, b2, m2, v2, g3, b3, m3, v3,
                                  wpb, w2b, w3b, w1b, c1s, c2s, c3s);
    meganet<<<NB, NT, 0, stream>>>(x, wpb, w2b, w3b, w1b, c1s, c2s, c3s,
                                   bp, wc, bc, outp);
}

// Round 8
// 125.373 us; speedup vs baseline: 1.0865x; 1.0221x over previous
//
#include <hip/hip_runtime.h>
#include <hip/hip_bf16.h>
#include <math.h>

typedef __attribute__((ext_vector_type(8))) short short8;     // 8 x16b = 4 VGPRs (MFMA A/B frag)
typedef __attribute__((ext_vector_type(8))) _Float16 half8;   // f16 MFMA frag
typedef __attribute__((ext_vector_type(4))) float floatx4;    // MFMA C/D frag

#define NB 256
#define NW 12          // waves per block. 1024-thr blocks pin VGPR cap to 64 on this toolchain
#define NT (NW * 64)   // (r3/r6: (1024,4) and (1024,1) both -> 64 VGPR + MB-scale spills). 768 it is.

// ---------------- workspace layout (bytes) ----------------
#define WPB_OFF 0u        // 32*288 f16 [oc][k=n*32+ic], rows>=18 zero (p_conv, unscaled)
#define W2B_OFF 18432u    // 32*288 f16, scaled by inv2[oc]
#define W3B_OFF 36864u    // 64*288 f16, scaled by inv3[oc]
#define W1B_OFF 73728u    // 32*32 f16 [oc][k=n*3+ic], k>=27 zero, scaled by inv1[oc]
#define C1S_OFF 75776u    // 32 f32 shift1
#define C2S_OFF 75904u    // 32 f32 shift2
#define C3S_OFF 76032u    // 64 f32 shift3

// ---------------- LDS layout (bytes) ----------------
#define L_IMG1 0            // 785*64 = 50240  (h1: 784 px + zero slot), f16, XOR-swizzled slices
#define L_U    50240        // 785*64 = 50240  (x staging, then h2 interior + zero slot)
#define L_OFFT 100480       // 12 waves * 2112: [0,576) otw f16 offsets, [576,1344) recA, [1344,2112) recB
#define L_WL   125824       // 64 rows * 592 B (wp+w2 rows, later w3 rows)
#define L_TOT  163712       // <= 163840 (160 KiB)

// ---- image slice swizzle ----
// Pixel p occupies 64 B = 4 x 16B slices; stored slice index = s ^ ((p>>1)&3).
// Swizzled base sp = (p<<6) | ((p&6)<<3); consumer of slice s XORs (s<<4).
// Bank start becomes f(p&7) instead of f(p&1): deterministic 8-way -> 2-way (free, m136);
// random bilinear gathers -> ~2.5-way inherent. Zero slot (784) all-zero, swizzle-invariant.

// ---- intra-wave LDS ordering ----
// otw / rec buffers are PER-WAVE private scratch. DS ops from one wave complete in
// program order, so counted lgkmcnt before a read's use also covers preceding writes.
// Zero-cost compile-time fence pins write-before-read order (validated r7: bit-identical).
#define LDS_FENCE() __asm__ volatile("" ::: "memory")

static __device__ __forceinline__ unsigned short f2h(float f) {
    _Float16 h = (_Float16)f;
    unsigned short u;
    __builtin_memcpy(&u, &h, 2);
    return u;
}
static __device__ __forceinline__ float h2f(unsigned short u) {
    _Float16 h;
    __builtin_memcpy(&h, &u, 2);
    return (float)h;
}

// pack two f32 -> packed f16 pair (RNE scalar conversions)
static __device__ __forceinline__ unsigned pkh(float a, float b) {
    _Float16 ha = (_Float16)a, hb = (_Float16)b;
    unsigned short ua, ub;
    __builtin_memcpy(&ua, &ha, 2);
    __builtin_memcpy(&ub, &hb, 2);
    return (unsigned)ua | ((unsigned)ub << 16);
}

static __device__ __forceinline__ half8 h8(uint4 u) {
    half8 r;
    __builtin_memcpy(&r, &u, 16);
    return r;
}

// ---- packed f16 FMA with op_sel broadcast of one half of A ----
static __device__ __forceinline__ unsigned pkmul_l(unsigned a, unsigned b) {
    unsigned d;
    asm("v_pk_mul_f16 %0, %1, %2 op_sel:[0,0] op_sel_hi:[0,1]"
        : "=v"(d) : "v"(a), "v"(b));
    return d;
}
static __device__ __forceinline__ unsigned pkfma_l(unsigned a, unsigned b, unsigned c) {
    unsigned d;
    asm("v_pk_fma_f16 %0, %1, %2, %3 op_sel:[0,0,0] op_sel_hi:[0,1,1]"
        : "=v"(d) : "v"(a), "v"(b), "v"(c));
    return d;
}
static __device__ __forceinline__ unsigned pkfma_h(unsigned a, unsigned b, unsigned c) {
    unsigned d;
    asm("v_pk_fma_f16 %0, %1, %2, %3 op_sel:[1,0,0] op_sel_hi:[1,1,1]"
        : "=v"(d) : "v"(a), "v"(b), "v"(c));
    return d;
}

// ------- weight prep: f16, pre-transposed, BN-scale-folded -------
__global__ void wcvt(const float* __restrict__ wp, const float* __restrict__ w2,
                     const float* __restrict__ w3, const float* __restrict__ w1,
                     const float* __restrict__ g1, const float* __restrict__ b1,
                     const float* __restrict__ m1, const float* __restrict__ v1,
                     const float* __restrict__ g2, const float* __restrict__ b2,
                     const float* __restrict__ m2, const float* __restrict__ v2,
                     const float* __restrict__ g3, const float* __restrict__ b3,
                     const float* __restrict__ m3, const float* __restrict__ v3,
                     unsigned short* __restrict__ wpb, unsigned short* __restrict__ w2b,
                     unsigned short* __restrict__ w3b, unsigned short* __restrict__ w1b,
                     float* __restrict__ c1s, float* __restrict__ c2s,
                     float* __restrict__ c3s)
{
    int t = blockIdx.x * 256 + threadIdx.x;
    if (t < 9216) {
        int oc = t / 288, k = t % 288;
        int n = k >> 5, ic = k & 31;
        wpb[t] = (oc < 18) ? f2h(wp[oc * 288 + ic * 9 + n]) : (unsigned short)0;
    } else if (t < 18432) {
        int i = t - 9216;
        int oc = i / 288, k = i % 288;
        int n = k >> 5, ic = k & 31;
        float inv = g2[oc] * rsqrtf(v2[oc] + 1e-5f);
        w2b[i] = f2h(w2[oc * 288 + ic * 9 + n] * inv);
    } else if (t < 36864) {
        int i = t - 18432;
        int oc = i / 288, k = i % 288;
        int n = k >> 5, ic = k & 31;
        float inv = g3[oc] * rsqrtf(v3[oc] + 1e-5f);
        w3b[i] = f2h(w3[oc * 288 + ic * 9 + n] * inv);
    } else if (t < 37888) {
        int i = t - 36864;        // i = oc*32 + k, k = n*3+ic
        int oc = i >> 5, k = i & 31;
        int n = k / 3, ic = k - n * 3;
        float inv = g1[oc] * rsqrtf(v1[oc] + 1e-5f);
        w1b[i] = (k < 27) ? f2h(w1[oc * 27 + ic * 9 + n] * inv) : (unsigned short)0;
    } else if (t < 37920) {
        int c = t - 37888;        // 0..31
        float inv = g1[c] * rsqrtf(v1[c] + 1e-5f);
        c1s[c] = b1[c] - m1[c] * inv;
    } else if (t < 37952) {
        int c = t - 37920;
        float inv = g2[c] * rsqrtf(v2[c] + 1e-5f);
        c2s[c] = b2[c] - m2[c] * inv;
    } else if (t < 38016) {
        int c = t - 37952;        // 0..63
        float inv = g3[c] * rsqrtf(v3[c] + 1e-5f);
        c3s[c] = b3[c] - m3[c] * inv;
    }
}

// ======= mega-kernel (12 waves): conv1 -> img1 -> p_conv+bilinear+conv2 -> uimg -> conv3+pool -> cls =======
__global__ __launch_bounds__(NT, 3) void meganet(
    const float* __restrict__ x,
    const unsigned short* __restrict__ wpb, const unsigned short* __restrict__ w2b,
    const unsigned short* __restrict__ w3b, const unsigned short* __restrict__ w1b,
    const float* __restrict__ c1s, const float* __restrict__ c2s,
    const float* __restrict__ c3s, const float* __restrict__ bp,
    const float* __restrict__ wc, const float* __restrict__ bc,
    float* __restrict__ outp)
{
    __shared__ __align__(16) unsigned char ALL[L_TOT];
    int t = threadIdx.x, b = blockIdx.x;
    int w = t >> 6, l = t & 63, col = l & 15, q = l >> 4;
    int qs = q << 4;                                           // slice XOR for this lane
    int chxA = ((col >> 3) << 4) | ((col & 7) * 2);            // channel col     (c<16)
    int chxB = ((((16 + col) >> 3) & 3) << 4) | ((col & 7) * 2); // channel 16+col

    unsigned char* img1 = ALL + L_IMG1;
    unsigned char* uimg = ALL + L_U;          // x staging then h2

    // ---- phase 0: stage x + weights into LDS (all coalesced) ----
    {
        const float4* xg = (const float4*)(x + (size_t)b * 2352);
        float4* xl = (float4*)uimg;
        for (int i = t; i < 588; i += NT) xl[i] = xg[i];
    }
    {
        const uint4* s1 = (const uint4*)wpb;
        const uint4* s2 = (const uint4*)w2b;
        for (int i = t; i < 2304; i += NT) {      // wp rows 0..31, w2 rows 32..63
            int row = i / 36, g = i - row * 36;
            uint4 v = (row < 32) ? s1[row * 36 + g] : s2[(row - 32) * 36 + g];
            *(uint4*)(ALL + L_WL + row * 592 + g * 16) = v;
        }
        if (t < 128) *(uint4*)(ALL + L_OFFT + t * 16) = ((const uint4*)w1b)[t];
    }
    if (t == 700) ((float*)uimg)[2352] = 0.f;                       // conv1 zero slot
    if (t < 4)  *(uint4*)(img1 + 784 * 64 + t * 16) = make_uint4(0u, 0u, 0u, 0u);
    if (t >= 4 && t < 8) *(uint4*)(uimg + 784 * 64 + (t - 4) * 16) = make_uint4(0u, 0u, 0u, 0u);

    float s0 = c1s[col], s1v = c1s[16 + col];
    float bias0 = bp[col];
    float bias1 = (col < 2) ? bp[16 + col] : 0.f;
    float sh0 = c2s[col], sh1 = c2s[16 + col];

    __syncthreads();

    // ---- phase 1: conv1 (3->32, pad1, relu, bn-folded) -> img1 (f16, swizzled) ----
    {
        half8 bf0 = h8(*(const uint4*)(ALL + L_OFFT + col * 64 + q * 16));
        half8 bf1 = h8(*(const uint4*)(ALL + L_OFFT + (16 + col) * 64 + q * 16));
        const float* xs = (const float*)uimg;
        for (int mt = w; mt < 49; mt += NW) {
            int p = mt * 16 + col;
            int y = p / 28, xx = p % 28;
            unsigned au[4];
#pragma unroll
            for (int jp = 0; jp < 4; jp++) {
                float vv[2];
#pragma unroll
                for (int h = 0; h < 2; h++) {
                    int k = q * 8 + jp * 2 + h;
                    int n = k / 3, ic = k - n * 3;
                    int yy = y + n / 3 - 1, xc = xx + n % 3 - 1;
                    bool ok = (k < 27) && ((unsigned)yy < 28u) && ((unsigned)xc < 28u);
                    int idx = ok ? (ic * 784 + yy * 28 + xc) : 2352;
                    vv[h] = xs[idx];
                }
                au[jp] = pkh(vv[0], vv[1]);
            }
            uint4 a4 = make_uint4(au[0], au[1], au[2], au[3]);
            half8 a = h8(a4);
            floatx4 d0 = {0.f, 0.f, 0.f, 0.f}, d1 = {0.f, 0.f, 0.f, 0.f};
            d0 = __builtin_amdgcn_mfma_f32_16x16x32_f16(a, bf0, d0, 0, 0, 0);
            d1 = __builtin_amdgcn_mfma_f32_16x16x32_f16(a, bf1, d1, 0, 0, 0);
#pragma unroll
            for (int r = 0; r < 4; r++) {
                int pout = mt * 16 + q * 4 + r;
                int sp = (pout << 6) | ((pout & 6) << 3);
                *(unsigned short*)(img1 + (sp ^ chxA)) = f2h(fmaxf(d0[r], 0.f) + s0);
                *(unsigned short*)(img1 + (sp ^ chxB)) = f2h(fmaxf(d1[r], 0.f) + s1v);
            }
        }
    }
    __syncthreads();

    // ---- phase 2: p_conv MFMA (split acc chains) -> offsets(f16) -> double-buffered record
    //      pipeline (pre(tg+1) overlaps consume(tg)) -> bilinear (packed f16) -> conv2 MFMA -> uimg ----
    {
        const unsigned char* ib = img1;
        unsigned char* wsc = ALL + L_OFFT + w * 2112;
        unsigned short* otw = (unsigned short*)wsc;   // [16 px][18 ch] f16 raw offsets (576 B)
        unsigned char* rec0 = wsc + 576;              // 48 records x 16 B
        unsigned char* rec1 = wsc + 1344;             // 48 records x 16 B

        // hoist conv2 B-frags into registers (loop-invariant; 72 VGPRs)
        half8 b2fr[18];
#pragma unroll
        for (int n = 0; n < 9; n++) {
            b2fr[n]     = h8(*(const uint4*)(ALL + L_WL + (32 + col) * 592 + n * 64 + q * 16));
            b2fr[9 + n] = h8(*(const uint4*)(ALL + L_WL + (48 + col) * 592 + n * 64 + q * 16));
        }

        for (int mt = w; mt < 49; mt += NW) {
            int p = mt * 16 + col;
            int y = p / 28, xx = p % 28;

            // p_conv for this 16-pixel tile; even/odd accumulator split (chain depth 9 -> ~4.5)
            floatx4 a0e = {0.f, 0.f, 0.f, 0.f}, a0o = {0.f, 0.f, 0.f, 0.f};
            floatx4 a1e = {0.f, 0.f, 0.f, 0.f}, a1o = {0.f, 0.f, 0.f, 0.f};
#pragma unroll
            for (int n = 0; n < 9; n++) {
                int yy = y + n / 3 - 1, xc = xx + n % 3 - 1;
                bool ok = ((unsigned)yy < 28u) && ((unsigned)xc < 28u);
                int tp = ok ? (yy * 28 + xc) : 784;      // 784 = zero slot
                int sp = (tp << 6) | ((tp & 6) << 3);
                half8 a  = h8(*(const uint4*)(ib + (sp ^ qs)));
                half8 p0 = h8(*(const uint4*)(ALL + L_WL + col * 592 + n * 64 + q * 16));
                half8 p1 = h8(*(const uint4*)(ALL + L_WL + (16 + col) * 592 + n * 64 + q * 16));
                if (n & 1) {
                    a0o = __builtin_amdgcn_mfma_f32_16x16x32_f16(a, p0, a0o, 0, 0, 0);
                    a1o = __builtin_amdgcn_mfma_f32_16x16x32_f16(a, p1, a1o, 0, 0, 0);
                } else {
                    a0e = __builtin_amdgcn_mfma_f32_16x16x32_f16(a, p0, a0e, 0, 0, 0);
                    a1e = __builtin_amdgcn_mfma_f32_16x16x32_f16(a, p1, a1e, 0, 0, 0);
                }
            }
            floatx4 a0 = a0e + a0o, a1 = a1e + a1o;
#pragma unroll
            for (int r = 0; r < 4; r++)
                otw[(q * 4 + r) * 18 + col] = f2h(a0[r] + bias0);
            if (col < 2) {
#pragma unroll
                for (int r = 0; r < 4; r++)
                    otw[(q * 4 + r) * 18 + 16 + col] = f2h(a1[r] + bias1);
            }
            LDS_FENCE();   // otw write -> read (in-order DS pipe, validated r7)

            // precompute: 48 combos (16 px x 3 taps of group tgi), records into buf
            auto pre = [&](int tgi, unsigned char* buf) {
                if (l < 48) {
                    int px = l & 15, n = tgi * 3 + (l >> 4);
                    int pg = mt * 16 + px;
                    int yg = pg / 28, xg = pg % 28;
                    float offy = h2f(otw[px * 18 + n]);
                    float offx = h2f(otw[px * 18 + 9 + n]);
                    float py = (float)(yg + n / 3) + offy;       // padded coords
                    float pxf = (float)(xg + n % 3) + offx;
                    float fy = floorf(py), fx = floorf(pxf);
                    float qy0 = fminf(fmaxf(fy, 0.f), 29.f);
                    float qy1 = fminf(fmaxf(fy + 1.f, 0.f), 29.f);
                    float qx0 = fminf(fmaxf(fx, 0.f), 29.f);
                    float qx1 = fminf(fmaxf(fx + 1.f, 0.f), 29.f);
                    float pyc = fminf(fmaxf(py, 0.f), 29.f);
                    float pxc = fminf(fmaxf(pxf, 0.f), 29.f);
                    float glt = (1.f + (qy0 - pyc)) * (1.f + (qx0 - pxc));
                    float grb = (1.f - (qy1 - pyc)) * (1.f - (qx1 - pxc));
                    float glb = (1.f + (qy0 - pyc)) * (1.f - (qx1 - pxc));
                    float grt = (1.f - (qy1 - pyc)) * (1.f + (qx0 - pxc));
                    int iy0 = (int)qy0, iy1 = (int)qy1, ix0 = (int)qx0, ix1 = (int)qx1;
                    int ly0 = iy0 - 1, ly1 = iy1 - 1, lx0 = ix0 - 1, lx1 = ix1 - 1;
                    bool v00 = ((unsigned)ly0 < 28u) && ((unsigned)lx0 < 28u);
                    bool v11 = ((unsigned)ly1 < 28u) && ((unsigned)lx1 < 28u);
                    bool v01 = ((unsigned)ly0 < 28u) && ((unsigned)lx1 < 28u);
                    bool v10 = ((unsigned)ly1 < 28u) && ((unsigned)lx0 < 28u);
                    unsigned p00 = v00 ? (unsigned)(ly0 * 28 + lx0) : 784u;
                    unsigned p11 = v11 ? (unsigned)(ly1 * 28 + lx1) : 784u;
                    unsigned p01 = v01 ? (unsigned)(ly0 * 28 + lx1) : 784u;
                    unsigned p10 = v10 ? (unsigned)(ly1 * 28 + lx0) : 784u;
                    // swizzled base offsets: (p<<6) | ((p&6)<<3) -- consumer XORs (q<<4)
                    unsigned s00 = (p00 << 6) | ((p00 & 6u) << 3);
                    unsigned s11 = (p11 << 6) | ((p11 & 6u) << 3);
                    unsigned s01 = (p01 << 6) | ((p01 & 6u) << 3);
                    unsigned s10 = (p10 << 6) | ((p10 & 6u) << 3);
                    uint4 rec = make_uint4(pkh(glt, grb), pkh(glb, grt),
                                           s00 | (s11 << 16), s01 | (s10 << 16));
                    *(uint4*)(buf + l * 16) = rec;
                }
            };

            floatx4 d0e = {0.f, 0.f, 0.f, 0.f}, d0o = {0.f, 0.f, 0.f, 0.f};
            floatx4 d1e = {0.f, 0.f, 0.f, 0.f}, d1o = {0.f, 0.f, 0.f, 0.f};
            pre(0, rec0);
#pragma unroll
            for (int tg = 0; tg < 3; tg++) {
                LDS_FENCE();   // orders prior writes before this iter's reads; prior reads before buffer reuse
                unsigned char* cur = (tg & 1) ? rec1 : rec0;
                unsigned char* nxt = (tg & 1) ? rec0 : rec1;
                if (tg < 2) pre(tg + 1, nxt);    // overlaps with consume below (disjoint buffers)

                // consume: 3 taps, record broadcast across quads; bilinear in packed f16
#pragma unroll
                for (int k3 = 0; k3 < 3; k3++) {
                    int n = tg * 3 + k3;
                    uint4 rec = *(const uint4*)(cur + (k3 * 16 + col) * 16);
                    unsigned o00 = (rec.z & 0xffffu) ^ qs, o11 = (rec.z >> 16) ^ qs;
                    unsigned o01 = (rec.w & 0xffffu) ^ qs, o10 = (rec.w >> 16) ^ qs;
                    uint4 u00 = *(const uint4*)(ib + o00);
                    uint4 u11 = *(const uint4*)(ib + o11);
                    uint4 u01 = *(const uint4*)(ib + o01);
                    uint4 u10 = *(const uint4*)(ib + o10);
                    // f = glt*u00 + grb*u11 + glb*u01 + grt*u10, all packed f16
                    unsigned f0 = pkfma_h(rec.y, u10.x,
                                  pkfma_l(rec.y, u01.x,
                                  pkfma_h(rec.x, u11.x,
                                  pkmul_l(rec.x, u00.x))));
                    unsigned f1 = pkfma_h(rec.y, u10.y,
                                  pkfma_l(rec.y, u01.y,
                                  pkfma_h(rec.x, u11.y,
                                  pkmul_l(rec.x, u00.y))));
                    unsigned f2 = pkfma_h(rec.y, u10.z,
                                  pkfma_l(rec.y, u01.z,
                                  pkfma_h(rec.x, u11.z,
                                  pkmul_l(rec.x, u00.z))));
                    unsigned f3 = pkfma_h(rec.y, u10.w,
                                  pkfma_l(rec.y, u01.w,
                                  pkfma_h(rec.x, u11.w,
                                  pkmul_l(rec.x, u00.w))));
                    uint4 af4 = make_uint4(f0, f1, f2, f3);
                    half8 af = h8(af4);
                    if (n & 1) {
                        d0o = __builtin_amdgcn_mfma_f32_16x16x32_f16(af, b2fr[n], d0o, 0, 0, 0);
                        d1o = __builtin_amdgcn_mfma_f32_16x16x32_f16(af, b2fr[9 + n], d1o, 0, 0, 0);
                    } else {
                        d0e = __builtin_amdgcn_mfma_f32_16x16x32_f16(af, b2fr[n], d0e, 0, 0, 0);
                        d1e = __builtin_amdgcn_mfma_f32_16x16x32_f16(af, b2fr[9 + n], d1e, 0, 0, 0);
                    }
                }
            }
            floatx4 d0 = d0e + d0o, d1 = d1e + d1o;
            // relu + shift2 + store to LDS uimg (swizzled, 64B/px, f16)
#pragma unroll
            for (int r = 0; r < 4; r++) {
                int pout = mt * 16 + q * 4 + r;
                int sp = (pout << 6) | ((pout & 6) << 3);
                *(unsigned short*)(uimg + (sp ^ chxA)) = f2h(fmaxf(d0[r], 0.f) + sh0);
                *(unsigned short*)(uimg + (sp ^ chxB)) = f2h(fmaxf(d1[r], 0.f) + sh1);
            }
        }
    }
    __syncthreads();

    // ---- phase 3: stage w3 (f16, pre-scaled) -> pool rows 0..63 (coalesced) ----
    {
        const uint4* src = (const uint4*)w3b;
        for (int i = t; i < 2304; i += NT) {
            int row = i / 36, g = i - row * 36;
            *(uint4*)(ALL + L_WL + row * 592 + g * 16) = src[row * 36 + g];
        }
    }
    __syncthreads();

    // ---- phase 4: conv3 MFMA (split acc chains) + relu + global-sum partials ----
    {
        float* part = (float*)(ALL + L_OFFT);   // [NW][32]
        int ocp = w & 1;
        const unsigned char* ib = uimg;

        half8 wfr[18];
#pragma unroll
        for (int n = 0; n < 9; n++) {
            wfr[n]     = h8(*(const uint4*)(ALL + L_WL + (ocp * 32 + col) * 592 + n * 64 + q * 16));
            wfr[9 + n] = h8(*(const uint4*)(ALL + L_WL + (ocp * 32 + 16 + col) * 592 + n * 64 + q * 16));
        }

        float psA = 0.f, psB = 0.f;
        for (int mt = (w >> 1); mt < 49; mt += (NW / 2)) {
            int p = mt * 16 + col;
            int y = p / 28, xx = p % 28;
            floatx4 cAe = {0.f, 0.f, 0.f, 0.f}, cAo = {0.f, 0.f, 0.f, 0.f};
            floatx4 cBe = {0.f, 0.f, 0.f, 0.f}, cBo = {0.f, 0.f, 0.f, 0.f};
#pragma unroll
            for (int n = 0; n < 9; n++) {
                int yy = y + n / 3 - 1, xc = xx + n % 3 - 1;
                bool ok = ((unsigned)yy < 28u) && ((unsigned)xc < 28u);
                int tp = ok ? (yy * 28 + xc) : 784;
                int sp = (tp << 6) | ((tp & 6) << 3);
                half8 a = h8(*(const uint4*)(ib + (sp ^ qs)));
                if (n & 1) {
                    cAo = __builtin_amdgcn_mfma_f32_16x16x32_f16(a, wfr[n], cAo, 0, 0, 0);
                    cBo = __builtin_amdgcn_mfma_f32_16x16x32_f16(a, wfr[9 + n], cBo, 0, 0, 0);
                } else {
                    cAe = __builtin_amdgcn_mfma_f32_16x16x32_f16(a, wfr[n], cAe, 0, 0, 0);
                    cBe = __builtin_amdgcn_mfma_f32_16x16x32_f16(a, wfr[9 + n], cBe, 0, 0, 0);
                }
            }
            floatx4 cA = cAe + cAo, cB = cBe + cBo;
            psA += fmaxf(cA[0], 0.f) + fmaxf(cA[1], 0.f) + fmaxf(cA[2], 0.f) + fmaxf(cA[3], 0.f);
            psB += fmaxf(cB[0], 0.f) + fmaxf(cB[1], 0.f) + fmaxf(cB[2], 0.f) + fmaxf(cB[3], 0.f);
        }
        psA += __shfl_xor(psA, 16, 64); psA += __shfl_xor(psA, 32, 64);
        psB += __shfl_xor(psB, 16, 64); psB += __shfl_xor(psB, 32, 64);
        if (l < 16) { part[w * 32 + l] = psA; part[w * 32 + 16 + l] = psB; }
    }
    __syncthreads();

    // ---- phase 5: classifier (one wave): shift3, mean, linear 64->10, log_softmax ----
    if (t < 64) {
        const float* part = (const float*)(ALL + L_OFFT);
        int hi = t >> 5, c = t & 31;
        float s = 0.f;
#pragma unroll
        for (int j = 0; j < NW / 2; j++) s += part[(2 * j + hi) * 32 + c];   // oc = t
        float feat = s * (1.f / 784.f) + c3s[t];
        float lg[10];
        float mx = -1e30f;
#pragma unroll
        for (int j = 0; j < 10; j++) {
            float v = feat * wc[j * 64 + t];
            v += __shfl_xor(v, 1, 64);  v += __shfl_xor(v, 2, 64);
            v += __shfl_xor(v, 4, 64);  v += __shfl_xor(v, 8, 64);
            v += __shfl_xor(v, 16, 64); v += __shfl_xor(v, 32, 64);
            lg[j] = v + bc[j];
            mx = fmaxf(mx, lg[j]);
        }
        float se = 0.f;
#pragma unroll
        for (int j = 0; j < 10; j++) se += expf(lg[j] - mx);
        float lse = logf(se);
#pragma unroll
        for (int j = 0; j < 10; j++)
            if (t == j) outp[(size_t)b * 10 + j] = lg[j] - mx - lse;
    }
}

extern "C" void kernel_launch(void* const* d_in, const int* in_sizes, int n_in,
                              void* d_out, int out_size, void* d_ws, size_t ws_size,
                              hipStream_t stream)
{
    (void)in_sizes; (void)n_in; (void)out_size; (void)ws_size;
    const float* x  = (const float*)d_in[0];
    const float* w1 = (const float*)d_in[1];
    const float* g1 = (const float*)d_in[2];
    const float* b1 = (const float*)d_in[3];
    const float* m1 = (const float*)d_in[4];
    const float* v1 = (const float*)d_in[5];
    const float* wp = (const float*)d_in[6];
    const float* bp = (const float*)d_in[7];
    const float* w2 = (const float*)d_in[8];
    const float* g2 = (const float*)d_in[9];
    const float* b2 = (const float*)d_in[10];
    const float* m2 = (const float*)d_in[11];
    const float* v2 = (const float*)d_in[12];
    const float* w3 = (const float*)d_in[13];
    const float* g3 = (const float*)d_in[14];
    const float* b3 = (const float*)d_in[15];
    const float* m3 = (const float*)d_in[16];
    const float* v3 = (const float*)d_in[17];
    const float* wc = (const float*)d_in[18];
    const float* bc = (const float*)d_in[19];
    float* outp = (float*)d_out;

    unsigned char* ws = (unsigned char*)d_ws;
    unsigned short* wpb = (unsigned short*)(ws + WPB_OFF);
    unsigned short* w2b = (unsigned short*)(ws + W2B_OFF);
    unsigned short* w3b = (unsigned short*)(ws + W3B_OFF);
    unsigned short* w1b = (unsigned short*)(ws + W1B_OFF);
    float* c1s = (float*)(ws + C1S_OFF);
    float* c2s = (float*)(ws + C2S_OFF);
    float* c3s = (float*)(ws + C3S_OFF);

    wcvt<<<149, 256, 0, stream>>>(wp, w2, w3, w1, g1, b1, m1, v1,
                                  g2, b2, m2, v2, g3, b3, m3, v3,
                                  wpb, w2b, w3b, w1b, c1s, c2s, c3s);
    meganet<<<NB, NT, 0, stream>>>(x, wpb, w2b, w3b, w1b, c1s, c2s, c3s,
                                   bp, wc, bc, outp);
}